// Round 7
// baseline (2160.173 us; speedup 1.0000x reference)
//
#include <hip/hip_runtime.h>

#define Tn 256
#define Bn 64
#define Xn 512
#define Hn 2048
#define Gn 8192  // 4*Hn
#define NWG 256

typedef short bf16x8 __attribute__((ext_vector_type(8)));
typedef float f32x4 __attribute__((ext_vector_type(4)));
typedef unsigned uint32x4 __attribute__((ext_vector_type(4)));

#define AL(p)    __hip_atomic_load((p), __ATOMIC_RELAXED, __HIP_MEMORY_SCOPE_AGENT)
#define AS(p, v) __hip_atomic_store((p), (v), __ATOMIC_RELAXED, __HIP_MEMORY_SCOPE_AGENT)
#define AADD(p, v) __hip_atomic_fetch_add((p), (v), __ATOMIC_RELAXED, __HIP_MEMORY_SCOPE_AGENT)

static __device__ __forceinline__ unsigned short f2bf(float f) {
    unsigned int u = __builtin_bit_cast(unsigned int, f);
    u += 0x7fffu + ((u >> 16) & 1u);
    return (unsigned short)(u >> 16);
}
static __device__ __forceinline__ float bf2f(unsigned short s) {
    unsigned int u = ((unsigned int)s) << 16;
    return __builtin_bit_cast(float, u);
}
static __device__ __forceinline__ void cvt4(const float* __restrict__ s,
                                            unsigned short* __restrict__ d, int i) {
    float4 v = ((const float4*)s)[i];
    ushort4 o;
    o.x = f2bf(v.x); o.y = f2bf(v.y); o.z = f2bf(v.z); o.w = f2bf(v.w);
    ((ushort4*)d)[i] = o;
}
static __device__ __forceinline__ float sigm(float x) {
    return 1.f / (1.f + __expf(-x));
}
static __device__ __forceinline__ float ftanh(float x) {
    float e = __expf(2.f * x);
    return (e - 1.f) / (e + 1.f);
}

// h buffer offset within the ring (bytes). RING: 257 buffers, index permuted.
template <int RING>
static __device__ __forceinline__ size_t hoff(int t) {
    if constexpr (RING) return (size_t)((t * 97) % 257) * 262144;
    else                return (size_t)(t & 1) * 262144;
}
template <int RING>
static __device__ __forceinline__ bf16x8 ldh(const unsigned short* p) {
    if constexpr (RING) {
        return *(const bf16x8*)p;
    } else {
        unsigned* q = (unsigned*)p;
        uint32x4 v;
        v[0] = AL(q + 0); v[1] = AL(q + 1); v[2] = AL(q + 2); v[3] = AL(q + 3);
        return __builtin_bit_cast(bf16x8, v);
    }
}
template <int RING>
static __device__ __forceinline__ float ldh1(const unsigned short* hb, int idx) {
    if constexpr (RING) {
        return bf2f(hb[idx]);
    } else {
        unsigned d = AL((unsigned*)(hb + (idx & ~1)));
        return bf2f((idx & 1) ? (unsigned short)(d >> 16) : (unsigned short)(d & 0xffffu));
    }
}

// ---------------- shard-counter barrier ----------------
// shards[s] (s=0..7, one 32B block) monotonically counts publishes of WGs s*32..s*32+31.
// All WGs done with step t-1  <=>  every shard >= 32*t.
static __device__ __forceinline__ void shards_wait(unsigned* sh, unsigned t, int l) {
    if (!t) return;
    const unsigned target = t * 32u;
    const bool mine = (l < 8);
    for (;;) {
        unsigned a = mine ? AL(sh + l) : target;
        if (__all(a >= target)) break;
        __builtin_amdgcn_s_sleep(1);
    }
}

// ---------------- prologue ----------------
__global__ void prologue3(const float* __restrict__ x, const float* __restrict__ h0,
                          const float* __restrict__ b_ih, const float* __restrict__ b_hh,
                          const float* __restrict__ w_ih,
                          unsigned short* __restrict__ Xb, unsigned short* __restrict__ XFrag,
                          unsigned short* __restrict__ hb0, float* __restrict__ bias,
                          unsigned* __restrict__ flags)
{
    int i = blockIdx.x * blockDim.x + threadIdx.x;
    const int n_x  = Tn * Bn * Xn / 4;  // 2097152
    const int n_xf = Gn * Xn / 4;       // 1048576
    const int n_h  = Bn * Hn / 4;       // 32768
    const int n_b  = Gn / 4;            // 2048
    if (i < n_x) { cvt4(x, Xb, i); return; }
    i -= n_x;
    if (i < n_xf) {
        // Wih -> per-WG B-fragment layout (32 KB per WG)
        int wg = i >> 12, r = i & 4095;
        int c = r >> 7, k = (r & 127) * 4;
        int g = c >> 3, u = c & 7;
        float4 v = *(const float4*)(w_ih + (size_t)(g * Hn + wg * 8 + u) * Xn + k);
        ushort4 o;
        o.x = f2bf(v.x); o.y = f2bf(v.y); o.z = f2bf(v.z); o.w = f2bf(v.w);
        int ct = c >> 4, kk = k >> 5, l = ((k >> 3) & 3) * 16 + (c & 15);
        *(ushort4*)((char*)XFrag + (size_t)wg * 32768 + (size_t)((ct * 16 + kk) * 64 + l) * 16 + (k & 7) * 2) = o;
        return;
    }
    i -= n_xf;
    if (i < n_h) {
        // h0 -> blocked bf16 layout: elem(row,unit) at ((unit>>3)*64+row)*8+(unit&7)
        int flat = i * 4;
        int row = flat >> 11, unit0 = flat & 2047;
        float4 v = ((const float4*)h0)[i];
        ushort4 o;
        o.x = f2bf(v.x); o.y = f2bf(v.y); o.z = f2bf(v.z); o.w = f2bf(v.w);
        int dst = (((unit0 >> 3) << 6) + row) * 8 + (unit0 & 7);
        *(ushort4*)(hb0 + dst) = o;
        return;
    }
    i -= n_h;
    if (i < n_b) {
        float4 a = ((const float4*)b_ih)[i];
        float4 b = ((const float4*)b_hh)[i];
        ((float4*)bias)[i] = make_float4(a.x + b.x, a.y + b.y, a.z + b.z, a.w + b.w);
        return;
    }
    i -= n_b;
    if (i < 256) flags[i] = 0u;
}

#define MFMA4(a0v, a1v) \
    acc00 = __builtin_amdgcn_mfma_f32_16x16x32_bf16((a0v), b0, acc00, 0, 0, 0); \
    acc10 = __builtin_amdgcn_mfma_f32_16x16x32_bf16((a1v), b0, acc10, 0, 0, 0); \
    acc01 = __builtin_amdgcn_mfma_f32_16x16x32_bf16((a0v), b1, acc01, 0, 0, 0); \
    acc11 = __builtin_amdgcn_mfma_f32_16x16x32_bf16((a1v), b1, acc11, 0, 0, 0);

// ---------------- persistent LSTM, 8 waves = 4 K-quarters x 2 row-halves ----------------
// w = tid>>6; kh = w>>1 in [0,4), rblk = w&1. Wave covers rows rblk*32..+31 (two 16-row subs)
// and K-quarter kh*512..+511. 4 MFMA per B-pair (B reused across both row subs).
// LDS: [0,131072) Whh B-frags; [131072,155648) RED (3 partials x 2 rblk x 64 x 16 f32);
//      [155648,155680) RED2.
template <int RING>
__global__ __launch_bounds__(512, 2) void lstm_persist4(
    const unsigned short* __restrict__ Xb, const unsigned short* __restrict__ XFrag,
    const float* __restrict__ bias, const float* __restrict__ c0,
    char* __restrict__ hbase, const float* __restrict__ w_hh,
    float* __restrict__ ys, float* __restrict__ hT, float* __restrict__ cT,
    unsigned* __restrict__ shards)
{
    extern __shared__ char smem[];
    const unsigned short* LW = (const unsigned short*)smem;
    float* RED  = (float*)(smem + 131072);
    float* RED2 = (float*)(smem + 155648);

    const int wg  = blockIdx.x;
    const int tid = threadIdx.x;
    const int U0  = wg * 8;

    // stage Whh slice -> LDS B-fragments (all 8 waves help)
    for (int i = tid; i < 32 * 512; i += 512) {
        int c = i >> 9, k = (i & 511) * 4;
        int g = c >> 3, u = c & 7;
        float4 v = *(const float4*)(w_hh + (size_t)(g * Hn + U0 + u) * Hn + k);
        ushort4 o;
        o.x = f2bf(v.x); o.y = f2bf(v.y); o.z = f2bf(v.z); o.w = f2bf(v.w);
        int ct = c >> 4, kk = k >> 5, l = ((k >> 3) & 3) * 16 + (c & 15);
        *(ushort4*)(smem + ((size_t)((ct * 64 + kk) * 64 + l) * 16 + (k & 7) * 2)) = o;
    }
    __syncthreads();

    const int w = tid >> 6, l = tid & 63;
    const int lm = l & 15, lh = l >> 4;
    const int kh = w >> 1, rblk = w & 1, rb = rblk * 32;
    const int kk0 = kh * 16;   // h-part: 16 chunks of K=32 per quarter
    const int kx0 = kh * 4;    // x-part: 4 chunks of K=32 per quarter

    const int u  = lm & 7;
    const bool hi = (lm & 8) != 0;

    float bi = 0.f, bf_ = 0.f, bg = 0.f, bo = 0.f;
    float cs[2][2] = {{0.f, 0.f}, {0.f, 0.f}};
    if (kh == 0) {
        bi  = bias[0 * Hn + U0 + u];
        bf_ = bias[1 * Hn + U0 + u];
        bg  = bias[2 * Hn + U0 + u];
        bo  = bias[3 * Hn + U0 + u];
        #pragma unroll
        for (int s = 0; s < 2; ++s)
            #pragma unroll
            for (int j = 0; j < 2; ++j)
                cs[s][j] = c0[(size_t)(rb + s * 16 + 4 * lh + (hi ? 2 : 0) + j) * Hn + U0 + u];
    }

    const char* xfb = (const char*)XFrag + (size_t)wg * 32768;
    const int srb = w - 2;                      // softmax unit-block for waves 2..5

    for (int t = 0; t < Tn; ++t) {
        const unsigned short* hb = (const unsigned short*)(hbase + hoff<RING>(t));
        unsigned short* hn = (unsigned short*)(hbase + hoff<RING>(t + 1));

        f32x4 acc00 = {0,0,0,0}, acc01 = {0,0,0,0}, acc10 = {0,0,0,0}, acc11 = {0,0,0,0};

        // ---- x-part (this wave's K-quarter of 512): before the shard wait ----
        {
            const unsigned short* xa0 = Xb + (size_t)(t * 64 + rb + lm) * Xn + lh * 8;
            const unsigned short* xa1 = xa0 + 16 * Xn;
            bf16x8 xA0[4], xA1[4];
            #pragma unroll
            for (int j = 0; j < 4; ++j) {
                xA0[j] = *(const bf16x8*)(xa0 + (kx0 + j) * 32);
                xA1[j] = *(const bf16x8*)(xa1 + (kx0 + j) * 32);
            }
            #pragma unroll
            for (int kkl = 0; kkl < 4; ++kkl) {
                bf16x8 b0 = *(const bf16x8*)(xfb + ((size_t)((0 * 16 + kx0 + kkl) * 64 + l) << 4));
                bf16x8 b1 = *(const bf16x8*)(xfb + ((size_t)((1 * 16 + kx0 + kkl) * 64 + l) << 4));
                MFMA4(xA0[kkl], xA1[kkl]);
            }
        }

        if (w == 0) shards_wait(shards, (unsigned)t, l);
        __syncthreads();

        // ---- h-part (this wave's K-quarter of 2048), depth-4x2 prefetch ----
        {
            const unsigned short* ha0 = hb + (size_t)(rb + lm) * 8;   // chunk g at +g*512
            const unsigned short* ha1 = ha0 + 128;                    // +16 rows
            bf16x8 aP0[4], aP1[4];
            #pragma unroll
            for (int j = 0; j < 4; ++j) {
                int g = (kk0 + j) * 4 + lh;
                aP0[j] = ldh<RING>(ha0 + (size_t)g * 512);
                aP1[j] = ldh<RING>(ha1 + (size_t)g * 512);
            }
            #pragma unroll 4
            for (int kkl = 0; kkl < 16; ++kkl) {
                bf16x8 a0v = aP0[kkl & 3], a1v = aP1[kkl & 3];
                if (kkl < 12) {
                    int g = (kk0 + kkl + 4) * 4 + lh;
                    aP0[kkl & 3] = ldh<RING>(ha0 + (size_t)g * 512);
                    aP1[kkl & 3] = ldh<RING>(ha1 + (size_t)g * 512);
                }
                bf16x8 b0 = *(const bf16x8*)(LW + ((size_t)((0 * 64 + kk0 + kkl) * 64 + l) << 3));
                bf16x8 b1 = *(const bf16x8*)(LW + ((size_t)((1 * 64 + kk0 + kkl) * 64 + l) << 3));
                MFMA4(a0v, a1v);
            }
        }

        const bool do_sm = (srb >= 0 && srb < 4) && (wg < Bn) && (t > 0);
        float sv[8];
        if (kh != 0) {
            // dump partials for the kh==0 combiner
            int idx = (((kh - 1) * 2 + rblk) * 64 + l) * 16;
            *(f32x4*)(RED + idx + 0)  = acc00;
            *(f32x4*)(RED + idx + 4)  = acc01;
            *(f32x4*)(RED + idx + 8)  = acc10;
            *(f32x4*)(RED + idx + 12) = acc11;
            if (do_sm) {
                // softmax phase A: waves 2..5 split the 2048-unit row (row = wg)
                int row = wg;
                float m = -1e30f;
                #pragma unroll
                for (int j = 0; j < 8; ++j) {
                    int uu = srb * 512 + j * 64 + l;
                    sv[j] = ldh1<RING>(hb, (uu >> 3) * 512 + row * 8 + (uu & 7));
                    m = fmaxf(m, sv[j]);
                }
                #pragma unroll
                for (int off = 32; off; off >>= 1) m = fmaxf(m, __shfl_xor(m, off));
                float s = 0.f;
                #pragma unroll
                for (int j = 0; j < 8; ++j) s += __expf(sv[j] - m);
                #pragma unroll
                for (int off = 32; off; off >>= 1) s += __shfl_xor(s, off);
                if (l == 0) { RED2[srb * 2] = m; RED2[srb * 2 + 1] = s; }
            }
        }
        __syncthreads();

        if (kh == 0) {
            // combine 3 K-quarter partials, then the cell
            #pragma unroll
            for (int p = 0; p < 3; ++p) {
                int idx = ((p * 2 + rblk) * 64 + l) * 16;
                acc00 += *(const f32x4*)(RED + idx + 0);
                acc01 += *(const f32x4*)(RED + idx + 4);
                acc10 += *(const f32x4*)(RED + idx + 8);
                acc11 += *(const f32x4*)(RED + idx + 12);
            }
            f32x4 sA[2], sB[2];
            #pragma unroll
            for (int r = 0; r < 4; ++r) {
                sA[0][r] = __shfl_xor(acc00[r], 8); sB[0][r] = __shfl_xor(acc01[r], 8);
                sA[1][r] = __shfl_xor(acc10[r], 8); sB[1][r] = __shfl_xor(acc11[r], 8);
            }
            #pragma unroll
            for (int s = 0; s < 2; ++s) {
                f32x4 aA = s ? acc10 : acc00;
                f32x4 aB = s ? acc11 : acc01;
                #pragma unroll
                for (int j = 0; j < 2; ++j) {
                    int r = (hi ? 2 : 0) + j;
                    float gi = (hi ? sA[s][r] : aA[r]) + bi;
                    float gf = (hi ? aA[r] : sA[s][r]) + bf_;
                    float gg = (hi ? sB[s][r] : aB[r]) + bg;
                    float go = (hi ? aB[r] : sB[s][r]) + bo;
                    float iv = sigm(gi), fv = sigm(gf), gv = ftanh(gg), ov = sigm(go);
                    float cc = cs[s][j];
                    float cn = fv * cc + iv * gv;
                    float hv = ov * ftanh(cn);
                    cs[s][j] = cn;
                    int rowg = rb + s * 16 + 4 * lh + (hi ? 2 : 0) + j;
                    // pack lane-pair (u, u^1) -> one coherent dword store
                    unsigned short mybf = f2bf(hv);
                    unsigned other = (unsigned)__shfl_xor((int)(unsigned)mybf, 1);
                    if (!(u & 1)) {
                        AS((unsigned*)(hn + (size_t)wg * 512 + rowg * 8 + u),
                           (unsigned)mybf | (other << 16));
                    }
                    if (t == Tn - 1) {
                        size_t off = (size_t)rowg * Hn + U0 + u;
                        hT[off] = hv;
                        cT[off] = cn;
                    }
                }
            }
        }
        __syncthreads();   // drains h stores (vmcnt(0) before barrier)
        if (tid == 0) AADD(shards + (wg >> 5), 1u);

        if (do_sm) {
            // softmax phase B after publish — off the critical path
            float m0 = RED2[0], sA0 = RED2[1], m1 = RED2[2], sB0 = RED2[3];
            float m2 = RED2[4], sC0 = RED2[5], m3 = RED2[6], sD0 = RED2[7];
            float gm = fmaxf(fmaxf(m0, m1), fmaxf(m2, m3));
            float gs = sA0 * __expf(m0 - gm) + sB0 * __expf(m1 - gm) +
                       sC0 * __expf(m2 - gm) + sD0 * __expf(m3 - gm);
            float inv = 1.f / gs;
            float* yr = ys + ((size_t)(t - 1) * Bn + wg) * Hn + srb * 512;
            #pragma unroll
            for (int j = 0; j < 8; ++j) yr[j * 64 + l] = __expf(sv[j] - gm) * inv;
        }
    }

    // ---- final softmax on h(Tn) ----
    if (w == 0) shards_wait(shards, (unsigned)Tn, l);
    __syncthreads();
    {
        const unsigned short* hfin = (const unsigned short*)(hbase + hoff<RING>(Tn));
        const bool act = (srb >= 0 && srb < 4) && (wg < Bn);
        float sv[8];
        if (act) {
            int row = wg;
            float m = -1e30f;
            #pragma unroll
            for (int j = 0; j < 8; ++j) {
                int uu = srb * 512 + j * 64 + l;
                sv[j] = ldh1<RING>(hfin, (uu >> 3) * 512 + row * 8 + (uu & 7));
                m = fmaxf(m, sv[j]);
            }
            #pragma unroll
            for (int off = 32; off; off >>= 1) m = fmaxf(m, __shfl_xor(m, off));
            float s = 0.f;
            #pragma unroll
            for (int j = 0; j < 8; ++j) s += __expf(sv[j] - m);
            #pragma unroll
            for (int off = 32; off; off >>= 1) s += __shfl_xor(s, off);
            if (l == 0) { RED2[srb * 2] = m; RED2[srb * 2 + 1] = s; }
        }
        __syncthreads();
        if (act) {
            float m0 = RED2[0], sA0 = RED2[1], m1 = RED2[2], sB0 = RED2[3];
            float m2 = RED2[4], sC0 = RED2[5], m3 = RED2[6], sD0 = RED2[7];
            float gm = fmaxf(fmaxf(m0, m1), fmaxf(m2, m3));
            float gs = sA0 * __expf(m0 - gm) + sB0 * __expf(m1 - gm) +
                       sC0 * __expf(m2 - gm) + sD0 * __expf(m3 - gm);
            float inv = 1.f / gs;
            float* yr = ys + ((size_t)(Tn - 1) * Bn + wg) * Hn + srb * 512;
            #pragma unroll
            for (int j = 0; j < 8; ++j) yr[j * 64 + l] = __expf(sv[j] - gm) * inv;
        }
    }
}

// ---------------- host ----------------
extern "C" void kernel_launch(void* const* d_in, const int* in_sizes, int n_in,
                              void* d_out, int out_size, void* d_ws, size_t ws_size,
                              hipStream_t stream) {
    const float* input = (const float*)d_in[0];
    const float* h0    = (const float*)d_in[1];
    const float* c0    = (const float*)d_in[2];
    const float* w_ih  = (const float*)d_in[3];
    const float* w_hh  = (const float*)d_in[4];
    const float* b_ih  = (const float*)d_in[5];
    const float* b_hh  = (const float*)d_in[6];

    float* ys = (float*)d_out;                    // [256][64][2048]
    float* hT = ys + (size_t)Tn * Bn * Hn;        // [64][2048]
    float* cT = hT + (size_t)Bn * Hn;             // [64][2048]

    char* wsb = (char*)d_ws;
    unsigned short* Xb  = (unsigned short*)wsb;                  // 16,777,216
    unsigned short* XF  = (unsigned short*)(wsb + 16777216);     //  8,388,608
    float* bias         = (float*)(wsb + 25165824);              //     32,768
    unsigned* flags     = (unsigned*)(wsb + 25198592);           //      1,024 (shards in [0..7])
    char* hbase         = wsb + 25199616;                        // h buffers
    const size_t need_ring = 25199616 + (size_t)257 * 262144;    // 92,570,624
    // bypass need = 25,199,616 + 524,288 = 25,723,904

    const int prol_items = Tn * Bn * Xn / 4 + Gn * Xn / 4 + Bn * Hn / 4 + Gn / 4 + 256;
    const int prol_blocks = (prol_items + 255) / 256;
    prologue3<<<dim3(prol_blocks), dim3(256), 0, stream>>>(
        input, h0, b_ih, b_hh, w_ih, Xb, XF, (unsigned short*)hbase, bias, flags);

    if (ws_size >= need_ring) {
        (void)hipFuncSetAttribute((const void*)lstm_persist4<1>,
                                  hipFuncAttributeMaxDynamicSharedMemorySize, 155680);
        lstm_persist4<1><<<dim3(NWG), dim3(512), 155680, stream>>>(
            Xb, XF, bias, c0, hbase, w_hh, ys, hT, cT, flags);
    } else {
        (void)hipFuncSetAttribute((const void*)lstm_persist4<0>,
                                  hipFuncAttributeMaxDynamicSharedMemorySize, 155680);
        lstm_persist4<0><<<dim3(NWG), dim3(512), 155680, stream>>>(
            Xb, XF, bias, c0, hbase, w_hh, ys, hT, cT, flags);
    }
}

// Round 8
// 1957.556 us; speedup vs baseline: 1.1035x; 1.1035x over previous
//
#include <hip/hip_runtime.h>

#define Tn 256
#define Bn 64
#define Xn 512
#define Hn 2048
#define Gn 8192  // 4*Hn
#define NWG 256

typedef short bf16x8 __attribute__((ext_vector_type(8)));
typedef float f32x4 __attribute__((ext_vector_type(4)));
typedef unsigned uint32x4 __attribute__((ext_vector_type(4)));

#define AL(p)    __hip_atomic_load((p), __ATOMIC_RELAXED, __HIP_MEMORY_SCOPE_AGENT)
#define AS(p, v) __hip_atomic_store((p), (v), __ATOMIC_RELAXED, __HIP_MEMORY_SCOPE_AGENT)
#define AADD(p, v) __hip_atomic_fetch_add((p), (v), __ATOMIC_RELAXED, __HIP_MEMORY_SCOPE_AGENT)

static __device__ __forceinline__ unsigned short f2bf(float f) {
    unsigned int u = __builtin_bit_cast(unsigned int, f);
    u += 0x7fffu + ((u >> 16) & 1u);
    return (unsigned short)(u >> 16);
}
static __device__ __forceinline__ float bf2f(unsigned short s) {
    unsigned int u = ((unsigned int)s) << 16;
    return __builtin_bit_cast(float, u);
}
static __device__ __forceinline__ void cvt4(const float* __restrict__ s,
                                            unsigned short* __restrict__ d, int i) {
    float4 v = ((const float4*)s)[i];
    ushort4 o;
    o.x = f2bf(v.x); o.y = f2bf(v.y); o.z = f2bf(v.z); o.w = f2bf(v.w);
    ((ushort4*)d)[i] = o;
}
static __device__ __forceinline__ float sigm(float x) {
    return 1.f / (1.f + __expf(-x));
}
static __device__ __forceinline__ float ftanh(float x) {
    float e = __expf(2.f * x);
    return (e - 1.f) / (e + 1.f);
}

// h buffer offset within the ring (bytes). RING: 257 buffers, index permuted.
template <int RING>
static __device__ __forceinline__ size_t hoff(int t) {
    if constexpr (RING) return (size_t)((t * 97) % 257) * 262144;
    else                return (size_t)(t & 1) * 262144;
}
template <int RING>
static __device__ __forceinline__ bf16x8 ldh(const unsigned short* p) {
    if constexpr (RING) {
        return *(const bf16x8*)p;
    } else {
        unsigned* q = (unsigned*)p;
        uint32x4 v;
        v[0] = AL(q + 0); v[1] = AL(q + 1); v[2] = AL(q + 2); v[3] = AL(q + 3);
        return __builtin_bit_cast(bf16x8, v);
    }
}
template <int RING>
static __device__ __forceinline__ float ldh1(const unsigned short* hb, int idx) {
    if constexpr (RING) {
        return bf2f(hb[idx]);
    } else {
        unsigned d = AL((unsigned*)(hb + (idx & ~1)));
        return bf2f((idx & 1) ? (unsigned short)(d >> 16) : (unsigned short)(d & 0xffffu));
    }
}

// ---------------- per-wave shard-pair wait ----------------
// shards[s*16] (s=0..7, 64B apart) monotonically counts publishes of WGs s*32..s*32+31.
// Slice s of h(t) ready <=> shards[s*16] >= 32*t. Lane 0 polls s0, lanes>=1 poll s1.
static __device__ __forceinline__ void pair_wait(unsigned* sh, int s0, int s1,
                                                 unsigned target, int l) {
    if (!target) return;
    unsigned* p = sh + ((l == 0) ? s0 : s1) * 16;
    for (;;) {
        unsigned a = AL(p);
        if (__all(a >= target)) break;
        __builtin_amdgcn_s_sleep(1);
    }
}

// ---------------- prologue ----------------
__global__ void prologue3(const float* __restrict__ x, const float* __restrict__ h0,
                          const float* __restrict__ b_ih, const float* __restrict__ b_hh,
                          const float* __restrict__ w_ih,
                          unsigned short* __restrict__ Xb, unsigned short* __restrict__ XFrag,
                          unsigned short* __restrict__ hb0, float* __restrict__ bias,
                          unsigned* __restrict__ flags)
{
    int i = blockIdx.x * blockDim.x + threadIdx.x;
    const int n_x  = Tn * Bn * Xn / 4;  // 2097152
    const int n_xf = Gn * Xn / 4;       // 1048576
    const int n_h  = Bn * Hn / 4;       // 32768
    const int n_b  = Gn / 4;            // 2048
    if (i < n_x) { cvt4(x, Xb, i); return; }
    i -= n_x;
    if (i < n_xf) {
        // Wih -> per-WG B-fragment layout (32 KB per WG)
        int wg = i >> 12, r = i & 4095;
        int c = r >> 7, k = (r & 127) * 4;
        int g = c >> 3, u = c & 7;
        float4 v = *(const float4*)(w_ih + (size_t)(g * Hn + wg * 8 + u) * Xn + k);
        ushort4 o;
        o.x = f2bf(v.x); o.y = f2bf(v.y); o.z = f2bf(v.z); o.w = f2bf(v.w);
        int ct = c >> 4, kk = k >> 5, l = ((k >> 3) & 3) * 16 + (c & 15);
        *(ushort4*)((char*)XFrag + (size_t)wg * 32768 + (size_t)((ct * 16 + kk) * 64 + l) * 16 + (k & 7) * 2) = o;
        return;
    }
    i -= n_xf;
    if (i < n_h) {
        // h0 -> blocked bf16 layout: elem(row,unit) at ((unit>>3)*64+row)*8+(unit&7)
        int flat = i * 4;
        int row = flat >> 11, unit0 = flat & 2047;
        float4 v = ((const float4*)h0)[i];
        ushort4 o;
        o.x = f2bf(v.x); o.y = f2bf(v.y); o.z = f2bf(v.z); o.w = f2bf(v.w);
        int dst = (((unit0 >> 3) << 6) + row) * 8 + (unit0 & 7);
        *(ushort4*)(hb0 + dst) = o;
        return;
    }
    i -= n_h;
    if (i < n_b) {
        float4 a = ((const float4*)b_ih)[i];
        float4 b = ((const float4*)b_hh)[i];
        ((float4*)bias)[i] = make_float4(a.x + b.x, a.y + b.y, a.z + b.z, a.w + b.w);
        return;
    }
    i -= n_b;
    if (i < 256) flags[i] = 0u;
}

#define MFMA4(a0v, a1v) \
    acc00 = __builtin_amdgcn_mfma_f32_16x16x32_bf16((a0v), b0, acc00, 0, 0, 0); \
    acc10 = __builtin_amdgcn_mfma_f32_16x16x32_bf16((a1v), b0, acc10, 0, 0, 0); \
    acc01 = __builtin_amdgcn_mfma_f32_16x16x32_bf16((a0v), b1, acc01, 0, 0, 0); \
    acc11 = __builtin_amdgcn_mfma_f32_16x16x32_bf16((a1v), b1, acc11, 0, 0, 0);

// ---------------- persistent LSTM, 8 waves = 4 K-quarters x 2 row-halves ----------------
// w = tid>>6; kh = w>>1 in [0,4), rblk = w&1. Wave covers rows rblk*32..+31 and
// K-quarter kh*512..+511 = shards {2kh, 2kh+1}. Per-wave slice gating: each wave
// polls only its own two shard counters (no block-wide pre-GEMM barrier).
// LDS: [0,131072) Whh B-frags; [131072,155648) RED 4 acc-regions x 6 slots x 64 lanes x 16B;
//      [155648,155680) RED2.
template <int RING>
__global__ __launch_bounds__(512, 2) void lstm_persist5(
    const unsigned short* __restrict__ Xb, const unsigned short* __restrict__ XFrag,
    const float* __restrict__ bias, const float* __restrict__ c0,
    char* __restrict__ hbase, const float* __restrict__ w_hh,
    float* __restrict__ ys, float* __restrict__ hT, float* __restrict__ cT,
    unsigned* __restrict__ shards)
{
    extern __shared__ char smem[];
    const unsigned short* LW = (const unsigned short*)smem;
    float* RED  = (float*)(smem + 131072);
    float* RED2 = (float*)(smem + 155648);

    const int wg  = blockIdx.x;
    const int tid = threadIdx.x;
    const int U0  = wg * 8;

    // stage Whh slice -> LDS B-fragments (all 8 waves help)
    for (int i = tid; i < 32 * 512; i += 512) {
        int c = i >> 9, k = (i & 511) * 4;
        int g = c >> 3, u = c & 7;
        float4 v = *(const float4*)(w_hh + (size_t)(g * Hn + U0 + u) * Hn + k);
        ushort4 o;
        o.x = f2bf(v.x); o.y = f2bf(v.y); o.z = f2bf(v.z); o.w = f2bf(v.w);
        int ct = c >> 4, kk = k >> 5, l = ((k >> 3) & 3) * 16 + (c & 15);
        *(ushort4*)(smem + ((size_t)((ct * 64 + kk) * 64 + l) * 16 + (k & 7) * 2)) = o;
    }
    __syncthreads();

    const int w = tid >> 6, l = tid & 63;
    const int lm = l & 15, lh = l >> 4;
    const int kh = w >> 1, rblk = w & 1, rb = rblk * 32;
    const int kk0 = kh * 16;   // h-part: 16 chunks of K=32 per quarter
    const int kx0 = kh * 4;    // x-part: 4 chunks of K=32 per quarter

    const int u  = lm & 15 & 7;
    const bool hi = (lm & 8) != 0;

    float bi = 0.f, bf_ = 0.f, bg = 0.f, bo = 0.f;
    float cs[2][2] = {{0.f, 0.f}, {0.f, 0.f}};
    if (kh == 0) {
        bi  = bias[0 * Hn + U0 + u];
        bf_ = bias[1 * Hn + U0 + u];
        bg  = bias[2 * Hn + U0 + u];
        bo  = bias[3 * Hn + U0 + u];
        #pragma unroll
        for (int s = 0; s < 2; ++s)
            #pragma unroll
            for (int j = 0; j < 2; ++j)
                cs[s][j] = c0[(size_t)(rb + s * 16 + 4 * lh + (hi ? 2 : 0) + j) * Hn + U0 + u];
    }

    const char* xfb = (const char*)XFrag + (size_t)wg * 32768;
    const int srb = w - 2;                      // softmax unit-block for waves 2..5

    for (int t = 0; t < Tn; ++t) {
        const unsigned short* hb = (const unsigned short*)(hbase + hoff<RING>(t));
        unsigned short* hn = (unsigned short*)(hbase + hoff<RING>(t + 1));

        f32x4 acc00 = {0,0,0,0}, acc01 = {0,0,0,0}, acc10 = {0,0,0,0}, acc11 = {0,0,0,0};

        // ---- x-part (this wave's K-quarter of 512): before the shard wait ----
        {
            const unsigned short* xa0 = Xb + (size_t)(t * 64 + rb + lm) * Xn + lh * 8;
            const unsigned short* xa1 = xa0 + 16 * Xn;
            bf16x8 xA0[4], xA1[4];
            #pragma unroll
            for (int j = 0; j < 4; ++j) {
                xA0[j] = *(const bf16x8*)(xa0 + (kx0 + j) * 32);
                xA1[j] = *(const bf16x8*)(xa1 + (kx0 + j) * 32);
            }
            #pragma unroll
            for (int kkl = 0; kkl < 4; ++kkl) {
                bf16x8 b0 = *(const bf16x8*)(xfb + ((size_t)((0 * 16 + kx0 + kkl) * 64 + l) << 4));
                bf16x8 b1 = *(const bf16x8*)(xfb + ((size_t)((1 * 16 + kx0 + kkl) * 64 + l) << 4));
                MFMA4(xA0[kkl], xA1[kkl]);
            }
        }

        // ---- per-wave slice gate: only this wave's two shards ----
        pair_wait(shards, 2 * kh, 2 * kh + 1, (unsigned)t * 32u, l);

        // ---- h-part (this wave's K-quarter of 2048), depth-4x2 prefetch ----
        {
            const unsigned short* ha0 = hb + (size_t)(rb + lm) * 8;   // chunk g at +g*512
            const unsigned short* ha1 = ha0 + 128;                    // +16 rows
            bf16x8 aP0[4], aP1[4];
            #pragma unroll
            for (int j = 0; j < 4; ++j) {
                int g = (kk0 + j) * 4 + lh;
                aP0[j] = ldh<RING>(ha0 + (size_t)g * 512);
                aP1[j] = ldh<RING>(ha1 + (size_t)g * 512);
            }
            #pragma unroll 4
            for (int kkl = 0; kkl < 16; ++kkl) {
                bf16x8 a0v = aP0[kkl & 3], a1v = aP1[kkl & 3];
                if (kkl < 12) {
                    int g = (kk0 + kkl + 4) * 4 + lh;
                    aP0[kkl & 3] = ldh<RING>(ha0 + (size_t)g * 512);
                    aP1[kkl & 3] = ldh<RING>(ha1 + (size_t)g * 512);
                }
                bf16x8 b0 = *(const bf16x8*)(LW + ((size_t)((0 * 64 + kk0 + kkl) * 64 + l) << 3));
                bf16x8 b1 = *(const bf16x8*)(LW + ((size_t)((1 * 64 + kk0 + kkl) * 64 + l) << 3));
                MFMA4(a0v, a1v);
            }
        }

        const bool do_sm = (srb >= 0 && srb < 4) && (wg < Bn) && (t > 0);
        float sv[8];
        if (kh != 0) {
            // dump partials: per-acc contiguous regions -> conflict-free ds_write_b128
            int slot = (kh - 1) * 2 + rblk;
            int base = (slot * 64 + l) * 4;
            *(f32x4*)(RED + 0 * 1536 + base) = acc00;
            *(f32x4*)(RED + 1 * 1536 + base) = acc01;
            *(f32x4*)(RED + 2 * 1536 + base) = acc10;
            *(f32x4*)(RED + 3 * 1536 + base) = acc11;
            if (do_sm) {
                // softmax phase A: waves 2..5 split the 2048-unit row (row = wg)
                pair_wait(shards, 2 * srb, 2 * srb + 1, (unsigned)t * 32u, l);
                int row = wg;
                float m = -1e30f;
                #pragma unroll
                for (int j = 0; j < 8; ++j) {
                    int uu = srb * 512 + j * 64 + l;
                    sv[j] = ldh1<RING>(hb, (uu >> 3) * 512 + row * 8 + (uu & 7));
                    m = fmaxf(m, sv[j]);
                }
                #pragma unroll
                for (int off = 32; off; off >>= 1) m = fmaxf(m, __shfl_xor(m, off));
                float s = 0.f;
                #pragma unroll
                for (int j = 0; j < 8; ++j) s += __expf(sv[j] - m);
                #pragma unroll
                for (int off = 32; off; off >>= 1) s += __shfl_xor(s, off);
                if (l == 0) { RED2[srb * 2] = m; RED2[srb * 2 + 1] = s; }
            }
        }
        __syncthreads();

        if (kh == 0) {
            // combine 3 K-quarter partials, then the cell
            #pragma unroll
            for (int p = 0; p < 3; ++p) {
                int base = ((p * 2 + rblk) * 64 + l) * 4;
                acc00 += *(const f32x4*)(RED + 0 * 1536 + base);
                acc01 += *(const f32x4*)(RED + 1 * 1536 + base);
                acc10 += *(const f32x4*)(RED + 2 * 1536 + base);
                acc11 += *(const f32x4*)(RED + 3 * 1536 + base);
            }
            f32x4 sA[2], sB[2];
            #pragma unroll
            for (int r = 0; r < 4; ++r) {
                sA[0][r] = __shfl_xor(acc00[r], 8); sB[0][r] = __shfl_xor(acc01[r], 8);
                sA[1][r] = __shfl_xor(acc10[r], 8); sB[1][r] = __shfl_xor(acc11[r], 8);
            }
            #pragma unroll
            for (int s = 0; s < 2; ++s) {
                f32x4 aA = s ? acc10 : acc00;
                f32x4 aB = s ? acc11 : acc01;
                #pragma unroll
                for (int j = 0; j < 2; ++j) {
                    int r = (hi ? 2 : 0) + j;
                    float gi = (hi ? sA[s][r] : aA[r]) + bi;
                    float gf = (hi ? aA[r] : sA[s][r]) + bf_;
                    float gg = (hi ? sB[s][r] : aB[r]) + bg;
                    float go = (hi ? aB[r] : sB[s][r]) + bo;
                    float iv = sigm(gi), fv = sigm(gf), gv = ftanh(gg), ov = sigm(go);
                    float cc = cs[s][j];
                    float cn = fv * cc + iv * gv;
                    float hv = ov * ftanh(cn);
                    cs[s][j] = cn;
                    int rowg = rb + s * 16 + 4 * lh + (hi ? 2 : 0) + j;
                    // pack lane-pair (u, u^1) -> one coherent dword store
                    unsigned short mybf = f2bf(hv);
                    unsigned other = (unsigned)__shfl_xor((int)(unsigned)mybf, 1);
                    if (!(u & 1)) {
                        AS((unsigned*)(hn + (size_t)wg * 512 + rowg * 8 + u),
                           (unsigned)mybf | (other << 16));
                    }
                    if (t == Tn - 1) {
                        size_t off = (size_t)rowg * Hn + U0 + u;
                        hT[off] = hv;
                        cT[off] = cn;
                    }
                }
            }
        }
        __syncthreads();   // drains h stores (vmcnt(0) before barrier)
        if (tid == 0) AADD(shards + (wg >> 5) * 16, 1u);

        if (do_sm) {
            // softmax phase B after publish — off the critical path
            float m0 = RED2[0], sA0 = RED2[1], m1 = RED2[2], sB0 = RED2[3];
            float m2 = RED2[4], sC0 = RED2[5], m3 = RED2[6], sD0 = RED2[7];
            float gm = fmaxf(fmaxf(m0, m1), fmaxf(m2, m3));
            float gs = sA0 * __expf(m0 - gm) + sB0 * __expf(m1 - gm) +
                       sC0 * __expf(m2 - gm) + sD0 * __expf(m3 - gm);
            float inv = 1.f / gs;
            float* yr = ys + ((size_t)(t - 1) * Bn + wg) * Hn + srb * 512;
            #pragma unroll
            for (int j = 0; j < 8; ++j) yr[j * 64 + l] = __expf(sv[j] - gm) * inv;
        }
    }

    // ---- final softmax on h(Tn) ----
    {
        const unsigned short* hfin = (const unsigned short*)(hbase + hoff<RING>(Tn));
        const bool act = (srb >= 0 && srb < 4) && (wg < Bn);
        float sv[8];
        if (act) {
            pair_wait(shards, 2 * srb, 2 * srb + 1, (unsigned)Tn * 32u, l);
            int row = wg;
            float m = -1e30f;
            #pragma unroll
            for (int j = 0; j < 8; ++j) {
                int uu = srb * 512 + j * 64 + l;
                sv[j] = ldh1<RING>(hfin, (uu >> 3) * 512 + row * 8 + (uu & 7));
                m = fmaxf(m, sv[j]);
            }
            #pragma unroll
            for (int off = 32; off; off >>= 1) m = fmaxf(m, __shfl_xor(m, off));
            float s = 0.f;
            #pragma unroll
            for (int j = 0; j < 8; ++j) s += __expf(sv[j] - m);
            #pragma unroll
            for (int off = 32; off; off >>= 1) s += __shfl_xor(s, off);
            if (l == 0) { RED2[srb * 2] = m; RED2[srb * 2 + 1] = s; }
        }
        __syncthreads();
        if (act) {
            float m0 = RED2[0], sA0 = RED2[1], m1 = RED2[2], sB0 = RED2[3];
            float m2 = RED2[4], sC0 = RED2[5], m3 = RED2[6], sD0 = RED2[7];
            float gm = fmaxf(fmaxf(m0, m1), fmaxf(m2, m3));
            float gs = sA0 * __expf(m0 - gm) + sB0 * __expf(m1 - gm) +
                       sC0 * __expf(m2 - gm) + sD0 * __expf(m3 - gm);
            float inv = 1.f / gs;
            float* yr = ys + ((size_t)(Tn - 1) * Bn + wg) * Hn + srb * 512;
            #pragma unroll
            for (int j = 0; j < 8; ++j) yr[j * 64 + l] = __expf(sv[j] - gm) * inv;
        }
    }
}

// ---------------- host ----------------
extern "C" void kernel_launch(void* const* d_in, const int* in_sizes, int n_in,
                              void* d_out, int out_size, void* d_ws, size_t ws_size,
                              hipStream_t stream) {
    const float* input = (const float*)d_in[0];
    const float* h0    = (const float*)d_in[1];
    const float* c0    = (const float*)d_in[2];
    const float* w_ih  = (const float*)d_in[3];
    const float* w_hh  = (const float*)d_in[4];
    const float* b_ih  = (const float*)d_in[5];
    const float* b_hh  = (const float*)d_in[6];

    float* ys = (float*)d_out;                    // [256][64][2048]
    float* hT = ys + (size_t)Tn * Bn * Hn;        // [64][2048]
    float* cT = hT + (size_t)Bn * Hn;             // [64][2048]

    char* wsb = (char*)d_ws;
    unsigned short* Xb  = (unsigned short*)wsb;                  // 16,777,216
    unsigned short* XF  = (unsigned short*)(wsb + 16777216);     //  8,388,608
    float* bias         = (float*)(wsb + 25165824);              //     32,768
    unsigned* flags     = (unsigned*)(wsb + 25198592);           //      1,024 (shards at s*16)
    char* hbase         = wsb + 25199616;                        // h buffers
    const size_t need_ring = 25199616 + (size_t)257 * 262144;    // 92,570,624
    // bypass need = 25,199,616 + 524,288 = 25,723,904

    const int prol_items = Tn * Bn * Xn / 4 + Gn * Xn / 4 + Bn * Hn / 4 + Gn / 4 + 256;
    const int prol_blocks = (prol_items + 255) / 256;
    prologue3<<<dim3(prol_blocks), dim3(256), 0, stream>>>(
        input, h0, b_ih, b_hh, w_ih, Xb, XF, (unsigned short*)hbase, bias, flags);

    if (ws_size >= need_ring) {
        (void)hipFuncSetAttribute((const void*)lstm_persist5<1>,
                                  hipFuncAttributeMaxDynamicSharedMemorySize, 155680);
        lstm_persist5<1><<<dim3(NWG), dim3(512), 155680, stream>>>(
            Xb, XF, bias, c0, hbase, w_hh, ys, hT, cT, flags);
    } else {
        (void)hipFuncSetAttribute((const void*)lstm_persist5<0>,
                                  hipFuncAttributeMaxDynamicSharedMemorySize, 155680);
        lstm_persist5<0><<<dim3(NWG), dim3(512), 155680, stream>>>(
            Xb, XF, bias, c0, hbase, w_hh, ys, hT, cT, flags);
    }
}